// Round 1
// baseline (1834.295 us; speedup 1.0000x reference)
//
#include <hip/hip_runtime.h>
#include <hip/hip_bf16.h>
#include <cstdint>
#include <cstddef>

#define NTOK   8192
#define DH     2048      // HIDDEN
#define DF     1376      // FFN
#define NE     8
#define CAP    1280      // int(1.25 * 8192 / 8)

#define BM 128
#define BN 128
#define BK 32
#define LDS_STR 40       // bf16 elems per LDS row: 32 + 8 pad = 80B (16B aligned, 8 distinct b128 start banks)

typedef __bf16 bf16x8 __attribute__((ext_vector_type(8)));
typedef float  f32x4  __attribute__((ext_vector_type(4)));

__device__ __forceinline__ uint32_t pk2(float a, float b) {
  float2 f; f.x = a; f.y = b;
  union { __hip_bfloat162 h; uint32_t u; } cv;
  cv.h = __float22bfloat162_rn(f);
  return cv.u;
}

__device__ __forceinline__ ushort bf16bits(float a) {
  return (ushort)(pk2(a, 0.f) & 0xFFFFu);
}

// ---------------- routing: rank/keep/slot (single block) ----------------
__global__ void routing_kernel(const int* __restrict__ idx, int* __restrict__ tok_slot) {
  __shared__ int cnt[256][NE];
  const int t = threadIdx.x;
  for (int s = t; s < NE * CAP; s += 256) tok_slot[s] = -1;

  // packed 16-bit per-expert counters (counts <= 8192 < 65536, no lane overflow)
  unsigned long long cA = 0ull, cB = 0ull;
  const int per = NTOK / 256;
  const int base = t * per;
  for (int i = 0; i < per; ++i) {
    int e = idx[base + i];
    unsigned long long inc = 1ull << ((e & 3) * 16);
    if (e < 4) cA += inc; else cB += inc;
  }
#pragma unroll
  for (int e = 0; e < 4; ++e) cnt[t][e]     = (int)((cA >> (e * 16)) & 0xFFFF);
#pragma unroll
  for (int e = 0; e < 4; ++e) cnt[t][4 + e] = (int)((cB >> (e * 16)) & 0xFFFF);
  __syncthreads();
  if (t < NE) {             // serial exclusive prefix per expert (256 iters, tiny)
    int run = 0;
    for (int i = 0; i < 256; ++i) { int c = cnt[i][t]; cnt[i][t] = run; run += c; }
  }
  __syncthreads();
  cA = 0ull; cB = 0ull;
#pragma unroll
  for (int e = 0; e < 4; ++e) cA |= (unsigned long long)(cnt[t][e] & 0xFFFF) << (e * 16);
#pragma unroll
  for (int e = 0; e < 4; ++e) cB |= (unsigned long long)(cnt[t][4 + e] & 0xFFFF) << (e * 16);
  for (int i = 0; i < per; ++i) {
    int token = base + i;
    int e = idx[token];
    int sh = (e & 3) * 16;
    int r = (int)(((e < 4 ? cA : cB) >> sh) & 0xFFFF);
    unsigned long long inc = 1ull << sh;
    if (e < 4) cA += inc; else cB += inc;
    if (r < CAP) tok_slot[e * CAP + r] = token;
  }
}

// ---------------- GEMM1: h = silu(Xe*Wg) .* (Xe*Wu), Xe gathered from x ----------------
__global__ __launch_bounds__(256, 2) void gemm_gateup(
    const float* __restrict__ x,
    const float* __restrict__ wg,
    const float* __restrict__ wu,
    const int* __restrict__ tok_slot,
    ushort* __restrict__ h)   // bf16 bits, [NE*CAP, DF]
{
  const int nt = blockIdx.x, mt = blockIdx.y, e = blockIdx.z;
  const int tid = threadIdx.x;
  const int lane = tid & 63, wid = tid >> 6;
  const int wr = wid >> 1, wc = wid & 1;
  const int l15 = lane & 15, l4 = lane >> 4;

  __shared__ __align__(16) ushort Al[BM * LDS_STR];
  __shared__ __align__(16) ushort Bg[BN * LDS_STR];
  __shared__ __align__(16) ushort Bu[BN * LDS_STR];
  __shared__ int tokc[BM];

  if (tid < BM) tokc[tid] = tok_slot[e * CAP + mt * BM + tid];

  f32x4 accG[4][4], accU[4][4];
#pragma unroll
  for (int i = 0; i < 4; ++i)
#pragma unroll
    for (int j = 0; j < 4; ++j) {
      accG[i][j] = (f32x4){0.f, 0.f, 0.f, 0.f};
      accU[i][j] = (f32x4){0.f, 0.f, 0.f, 0.f};
    }

  const int n0 = nt * BN;
  const int bn = tid & 127;      // B staging: local n
  const int bkh = tid >> 7;      // B staging: k half (0/1)
  const int nglob = n0 + bn;
  const bool nv = (nglob < DF);
  const float* wgb = wg + (size_t)e * DH * DF + nglob;
  const float* wub = wu + (size_t)e * DH * DF + nglob;

  for (int kk = 0; kk < DH; kk += BK) {
    __syncthreads();
    // ---- stage A (gather token rows, f32 -> bf16): u -> row=u>>2, k-octet=u&3
#pragma unroll
    for (int i = 0; i < 2; ++i) {
      int u = tid + 256 * i;
      int row = u >> 2, oct = u & 3;
      int tk = tokc[row];
      float4 v0 = {0.f,0.f,0.f,0.f}, v1 = {0.f,0.f,0.f,0.f};
      if (tk >= 0) {
        const float* p = x + (size_t)tk * DH + kk + oct * 8;
        v0 = *(const float4*)p;
        v1 = *(const float4*)(p + 4);
      }
      uint4 pk = { pk2(v0.x, v0.y), pk2(v0.z, v0.w), pk2(v1.x, v1.y), pk2(v1.z, v1.w) };
      *(uint4*)&Al[row * LDS_STR + oct * 8] = pk;
    }
    // ---- stage Bg/Bu (k-gather transpose, f32 -> bf16)
#pragma unroll
    for (int o2 = 0; o2 < 2; ++o2) {
      int klo = kk + bkh * 16 + o2 * 8;
      const float* pg = wgb + (size_t)klo * DF;
      const float* pu = wub + (size_t)klo * DF;
      float g[8], uu[8];
#pragma unroll
      for (int j = 0; j < 8; ++j) {
        g[j]  = nv ? pg[(size_t)j * DF] : 0.f;
        uu[j] = nv ? pu[(size_t)j * DF] : 0.f;
      }
      uint4 pkg = { pk2(g[0],g[1]),  pk2(g[2],g[3]),  pk2(g[4],g[5]),  pk2(g[6],g[7]) };
      uint4 pku = { pk2(uu[0],uu[1]), pk2(uu[2],uu[3]), pk2(uu[4],uu[5]), pk2(uu[6],uu[7]) };
      int oct = bkh * 2 + o2;
      *(uint4*)&Bg[bn * LDS_STR + oct * 8] = pkg;
      *(uint4*)&Bu[bn * LDS_STR + oct * 8] = pku;
    }
    __syncthreads();
    // ---- compute: 32 MFMA per wave per K-step
    bf16x8 af[4];
#pragma unroll
    for (int i = 0; i < 4; ++i)
      af[i] = *(const bf16x8*)&Al[(wr * 64 + i * 16 + l15) * LDS_STR + l4 * 8];
#pragma unroll
    for (int j = 0; j < 4; ++j) {
      bf16x8 bgf = *(const bf16x8*)&Bg[(wc * 64 + j * 16 + l15) * LDS_STR + l4 * 8];
      bf16x8 buf = *(const bf16x8*)&Bu[(wc * 64 + j * 16 + l15) * LDS_STR + l4 * 8];
#pragma unroll
      for (int i = 0; i < 4; ++i) {
        accG[i][j] = __builtin_amdgcn_mfma_f32_16x16x32_bf16(af[i], bgf, accG[i][j], 0, 0, 0);
        accU[i][j] = __builtin_amdgcn_mfma_f32_16x16x32_bf16(af[i], buf, accU[i][j], 0, 0, 0);
      }
    }
  }
  // ---- epilogue: SwiGLU, store bf16 h
  const int rowg0 = e * CAP + mt * BM + wr * 64;
#pragma unroll
  for (int j = 0; j < 4; ++j) {
    int col = n0 + wc * 64 + j * 16 + l15;
    if (col < DF) {
#pragma unroll
      for (int i = 0; i < 4; ++i) {
#pragma unroll
        for (int r = 0; r < 4; ++r) {
          int row = rowg0 + i * 16 + l4 * 4 + r;
          float gv = accG[i][j][r];
          float uv = accU[i][j][r];
          float val = gv / (1.f + __expf(-gv)) * uv;
          h[(size_t)row * DF + col] = bf16bits(val);
        }
      }
    }
  }
}

// ---------------- GEMM2: y[token] = (H * Wd) * score, scatter ----------------
__global__ __launch_bounds__(256, 2) void gemm_down(
    const ushort* __restrict__ h,
    const float* __restrict__ wd,
    const int* __restrict__ tok_slot,
    const float* __restrict__ scores,
    float* __restrict__ y)
{
  const int nt = blockIdx.x, mt = blockIdx.y, e = blockIdx.z;
  const int tid = threadIdx.x;
  const int lane = tid & 63, wid = tid >> 6;
  const int wr = wid >> 1, wc = wid & 1;
  const int l15 = lane & 15, l4 = lane >> 4;

  __shared__ __align__(16) ushort Al[BM * LDS_STR];
  __shared__ __align__(16) ushort Bl[BN * LDS_STR];
  __shared__ int tokc[BM];
  __shared__ float scc[BM];

  if (tid < BM) {
    int tk = tok_slot[e * CAP + mt * BM + tid];
    tokc[tid] = tk;
    scc[tid] = (tk >= 0) ? scores[tk] : 0.f;
  }

  f32x4 acc[4][4];
#pragma unroll
  for (int i = 0; i < 4; ++i)
#pragma unroll
    for (int j = 0; j < 4; ++j) acc[i][j] = (f32x4){0.f, 0.f, 0.f, 0.f};

  const int n0 = nt * BN;
  const int bn = tid & 127, bkh = tid >> 7;
  const float* wdb = wd + (size_t)e * DF * DH + n0 + bn;
  const size_t hrow0 = (size_t)(e * CAP + mt * BM);

  for (int kk = 0; kk < DF; kk += BK) {
    __syncthreads();
    // A: already bf16, straight copy
#pragma unroll
    for (int i = 0; i < 2; ++i) {
      int u = tid + 256 * i;
      int row = u >> 2, oct = u & 3;
      uint4 v = *(const uint4*)&h[(hrow0 + row) * DF + kk + oct * 8];
      *(uint4*)&Al[row * LDS_STR + oct * 8] = v;
    }
    // B: k-gather transpose + convert
#pragma unroll
    for (int o2 = 0; o2 < 2; ++o2) {
      int klo = kk + bkh * 16 + o2 * 8;
      const float* p = wdb + (size_t)klo * DH;
      float g[8];
#pragma unroll
      for (int j = 0; j < 8; ++j) g[j] = p[(size_t)j * DH];
      uint4 pkv = { pk2(g[0],g[1]), pk2(g[2],g[3]), pk2(g[4],g[5]), pk2(g[6],g[7]) };
      *(uint4*)&Bl[bn * LDS_STR + (bkh * 2 + o2) * 8] = pkv;
    }
    __syncthreads();
    bf16x8 af[4];
#pragma unroll
    for (int i = 0; i < 4; ++i)
      af[i] = *(const bf16x8*)&Al[(wr * 64 + i * 16 + l15) * LDS_STR + l4 * 8];
#pragma unroll
    for (int j = 0; j < 4; ++j) {
      bf16x8 bf = *(const bf16x8*)&Bl[(wc * 64 + j * 16 + l15) * LDS_STR + l4 * 8];
#pragma unroll
      for (int i = 0; i < 4; ++i)
        acc[i][j] = __builtin_amdgcn_mfma_f32_16x16x32_bf16(af[i], bf, acc[i][j], 0, 0, 0);
    }
  }
  // epilogue: scatter rows to tokens, * score (SCORE_SCALE == 1)
  int tkr[4][4]; float sr[4][4];
#pragma unroll
  for (int i = 0; i < 4; ++i)
#pragma unroll
    for (int r = 0; r < 4; ++r) {
      int rl = wr * 64 + i * 16 + l4 * 4 + r;
      tkr[i][r] = tokc[rl];
      sr[i][r]  = scc[rl];
    }
#pragma unroll
  for (int j = 0; j < 4; ++j) {
    int col = n0 + wc * 64 + j * 16 + l15;
#pragma unroll
    for (int i = 0; i < 4; ++i)
#pragma unroll
      for (int r = 0; r < 4; ++r)
        if (tkr[i][r] >= 0)
          y[(size_t)tkr[i][r] * DH + col] = acc[i][j][r] * sr[i][r];
  }
}

extern "C" void kernel_launch(void* const* d_in, const int* in_sizes, int n_in,
                              void* d_out, int out_size, void* d_ws, size_t ws_size,
                              hipStream_t stream) {
  const float* x   = (const float*)d_in[0];
  const int*   idx = (const int*)d_in[1];
  const float* sc  = (const float*)d_in[2];
  const float* wg  = (const float*)d_in[3];
  const float* wu  = (const float*)d_in[4];
  const float* wd  = (const float*)d_in[5];
  float* y = (float*)d_out;

  int* tok_slot = (int*)d_ws;                               // NE*CAP ints (40KB)
  ushort* h = (ushort*)((char*)d_ws + (1 << 16));           // bf16 [NE*CAP, DF] (~27.5MB)

  // dropped tokens -> 0
  hipMemsetAsync(d_out, 0, (size_t)out_size * sizeof(float), stream);

  hipLaunchKernelGGL(routing_kernel, dim3(1), dim3(256), 0, stream, idx, tok_slot);
  hipLaunchKernelGGL(gemm_gateup, dim3((DF + BN - 1) / BN, CAP / BM, NE), dim3(256), 0, stream,
                     x, wg, wu, tok_slot, h);
  hipLaunchKernelGGL(gemm_down, dim3(DH / BN, CAP / BM, NE), dim3(256), 0, stream,
                     h, wd, tok_slot, sc, y);
}

// Round 2
// 411.554 us; speedup vs baseline: 4.4570x; 4.4570x over previous
//
#include <hip/hip_runtime.h>
#include <hip/hip_bf16.h>
#include <cstdint>
#include <cstddef>

#define NTOK   8192
#define DH     2048      // HIDDEN
#define DF     1376      // FFN
#define NE     8
#define CAP    1280      // int(1.25 * 8192 / 8)

#define BM 128
#define BN 128
#define BK 32
#define LDS_STR 40       // v1 fallback: 32 + 8 pad

typedef __bf16 bf16x8 __attribute__((ext_vector_type(8)));
typedef float  f32x4  __attribute__((ext_vector_type(4)));

__device__ __forceinline__ uint32_t pk2(float a, float b) {
  float2 f; f.x = a; f.y = b;
  union { __hip_bfloat162 h; uint32_t u; } cv;
  cv.h = __float22bfloat162_rn(f);
  return cv.u;
}

__device__ __forceinline__ ushort bf16bits(float a) {
  return (ushort)(pk2(a, 0.f) & 0xFFFFu);
}

// async global->LDS, 16B per lane; LDS dest = wave-uniform base + lane*16
__device__ __forceinline__ void gload16(const ushort* g, ushort* l) {
  __builtin_amdgcn_global_load_lds(
      (const __attribute__((address_space(1))) uint32_t*)(const void*)g,
      (__attribute__((address_space(3))) uint32_t*)(void*)l,
      16, 0, 0);
}

// ---------------- routing: rank/keep/slot (single block) ----------------
__global__ void routing_kernel(const int* __restrict__ idx, int* __restrict__ tok_slot) {
  __shared__ int cnt[256][NE];
  const int t = threadIdx.x;
  for (int s = t; s < NE * CAP; s += 256) tok_slot[s] = -1;

  unsigned long long cA = 0ull, cB = 0ull;
  const int per = NTOK / 256;
  const int base = t * per;
  for (int i = 0; i < per; ++i) {
    int e = idx[base + i];
    unsigned long long inc = 1ull << ((e & 3) * 16);
    if (e < 4) cA += inc; else cB += inc;
  }
#pragma unroll
  for (int e = 0; e < 4; ++e) cnt[t][e]     = (int)((cA >> (e * 16)) & 0xFFFF);
#pragma unroll
  for (int e = 0; e < 4; ++e) cnt[t][4 + e] = (int)((cB >> (e * 16)) & 0xFFFF);
  __syncthreads();
  if (t < NE) {
    int run = 0;
    for (int i = 0; i < 256; ++i) { int c = cnt[i][t]; cnt[i][t] = run; run += c; }
  }
  __syncthreads();
  cA = 0ull; cB = 0ull;
#pragma unroll
  for (int e = 0; e < 4; ++e) cA |= (unsigned long long)(cnt[t][e] & 0xFFFF) << (e * 16);
#pragma unroll
  for (int e = 0; e < 4; ++e) cB |= (unsigned long long)(cnt[t][4 + e] & 0xFFFF) << (e * 16);
  for (int i = 0; i < per; ++i) {
    int token = base + i;
    int e = idx[token];
    int sh = (e & 3) * 16;
    int r = (int)(((e < 4 ? cA : cB) >> sh) & 0xFFFF);
    unsigned long long inc = 1ull << sh;
    if (e < 4) cA += inc; else cB += inc;
    if (r < CAP) tok_slot[e * CAP + r] = token;
  }
}

// ---------------- prep: x f32 -> bf16 ----------------
__global__ void convert_x(const float* __restrict__ x, ushort* __restrict__ xb) {
  int i = (blockIdx.x * 256 + threadIdx.x) * 8;
  float4 a = *(const float4*)(x + i);
  float4 b = *(const float4*)(x + i + 4);
  uint4 p = { pk2(a.x, a.y), pk2(a.z, a.w), pk2(b.x, b.y), pk2(b.z, b.w) };
  *(uint4*)(xb + i) = p;
}

// ---------------- prep: w [E][K][N] f32 -> [E][N][K] bf16 ----------------
__global__ __launch_bounds__(256) void transpose_cvt(
    const float* __restrict__ in, ushort* __restrict__ out, int K, int N) {
  __shared__ ushort T[64][72];
  const int tid = threadIdx.x;
  const int n0 = blockIdx.x * 64, k0 = blockIdx.y * 64;
  const size_t eoff_in  = (size_t)blockIdx.z * K * N;
  const size_t eoff_out = (size_t)blockIdx.z * N * K;
  const int kr = tid >> 4;         // 0..15
  const int nc = (tid & 15) * 4;   // 0..60
#pragma unroll
  for (int it = 0; it < 4; ++it) {
    int k = k0 + kr + it * 16;
    int n = n0 + nc;
    float4 v = {0.f, 0.f, 0.f, 0.f};
    if (k < K && n + 4 <= N) v = *(const float4*)(in + eoff_in + (size_t)k * N + n);
    T[nc + 0][kr + it * 16] = bf16bits(v.x);
    T[nc + 1][kr + it * 16] = bf16bits(v.y);
    T[nc + 2][kr + it * 16] = bf16bits(v.z);
    T[nc + 3][kr + it * 16] = bf16bits(v.w);
  }
  __syncthreads();
  const int nr = tid >> 2;         // 0..63
  const int kc = tid & 3;
#pragma unroll
  for (int it = 0; it < 2; ++it) {
    int kloc = kc * 16 + it * 8;
    int n = n0 + nr, k = k0 + kloc;
    if (n < N && k + 8 <= K)
      *(uint4*)(out + eoff_out + (size_t)n * K + k) = *(const uint4*)&T[nr][kloc];
  }
}

// ---------------- fast GEMM1: h = silu(Xe*Wg) .* (Xe*Wu) ----------------
__global__ __launch_bounds__(256, 2) void gemm_gateup2(
    const ushort* __restrict__ xb,
    const ushort* __restrict__ wgt,   // [E][DF][DH] bf16
    const ushort* __restrict__ wut,
    const int* __restrict__ tok_slot,
    ushort* __restrict__ h)
{
  const int nt = blockIdx.x, mt = blockIdx.y, e = blockIdx.z;
  const int tid = threadIdx.x, lane = tid & 63, wid = tid >> 6;
  const int wr = wid >> 1, wc = wid & 1;
  const int l15 = lane & 15, l4 = lane >> 4;

  __shared__ __align__(16) ushort Al[BM * BK];
  __shared__ __align__(16) ushort Bg[BN * BK];
  __shared__ __align__(16) ushort Bu[BN * BK];

  const int n0 = nt * BN;
  const int rlane = lane >> 2;   // row within 16-row chunk
  const int oct   = lane & 3;    // which 16B of the 64B row

  const ushort* srcA[2]; const ushort* srcBg[2]; const ushort* srcBu[2];
  int ldsoff[2];
#pragma unroll
  for (int c = 0; c < 2; ++c) {
    int chunk = wid * 2 + c;                 // 0..7
    int row = chunk * 16 + rlane;            // 0..127
    int tk = tok_slot[e * CAP + mt * BM + row];
    if (tk < 0) tk = 0;                      // finite garbage; output discarded
    srcA[c] = xb + (size_t)tk * DH + oct * 8;
    int n = n0 + row; if (n > DF - 1) n = DF - 1;
    srcBg[c] = wgt + ((size_t)e * DF + n) * DH + oct * 8;
    srcBu[c] = wut + ((size_t)e * DF + n) * DH + oct * 8;
    ldsoff[c] = chunk * 512;                 // linear [128][32] bf16
  }

  f32x4 accG[4][4], accU[4][4];
#pragma unroll
  for (int i = 0; i < 4; ++i)
#pragma unroll
    for (int j = 0; j < 4; ++j) {
      accG[i][j] = (f32x4){0.f, 0.f, 0.f, 0.f};
      accU[i][j] = (f32x4){0.f, 0.f, 0.f, 0.f};
    }

  for (int kk = 0; kk < DH; kk += BK) {
    __syncthreads();
#pragma unroll
    for (int c = 0; c < 2; ++c) {
      gload16(srcA[c]  + kk, &Al[ldsoff[c]]);
      gload16(srcBg[c] + kk, &Bg[ldsoff[c]]);
      gload16(srcBu[c] + kk, &Bu[ldsoff[c]]);
    }
    __syncthreads();
    bf16x8 af[4];
#pragma unroll
    for (int i = 0; i < 4; ++i)
      af[i] = *(const bf16x8*)&Al[(wr * 64 + i * 16 + l15) * BK + l4 * 8];
#pragma unroll
    for (int j = 0; j < 4; ++j) {
      bf16x8 bgf = *(const bf16x8*)&Bg[(wc * 64 + j * 16 + l15) * BK + l4 * 8];
      bf16x8 buf = *(const bf16x8*)&Bu[(wc * 64 + j * 16 + l15) * BK + l4 * 8];
#pragma unroll
      for (int i = 0; i < 4; ++i) {
        accG[i][j] = __builtin_amdgcn_mfma_f32_16x16x32_bf16(af[i], bgf, accG[i][j], 0, 0, 0);
        accU[i][j] = __builtin_amdgcn_mfma_f32_16x16x32_bf16(af[i], buf, accU[i][j], 0, 0, 0);
      }
    }
  }
  const int rowg0 = e * CAP + mt * BM + wr * 64;
#pragma unroll
  for (int j = 0; j < 4; ++j) {
    int col = n0 + wc * 64 + j * 16 + l15;
    if (col < DF) {
#pragma unroll
      for (int i = 0; i < 4; ++i) {
#pragma unroll
        for (int r = 0; r < 4; ++r) {
          int row = rowg0 + i * 16 + l4 * 4 + r;
          float gv = accG[i][j][r];
          float uv = accU[i][j][r];
          float val = gv / (1.f + __expf(-gv)) * uv;
          h[(size_t)row * DF + col] = bf16bits(val);
        }
      }
    }
  }
}

// ---------------- fast GEMM2: y[token] = (H * Wd) * score ----------------
__global__ __launch_bounds__(256, 3) void gemm_down2(
    const ushort* __restrict__ h,
    const ushort* __restrict__ wdt,   // [E][DH][DF] bf16
    const int* __restrict__ tok_slot,
    const float* __restrict__ scores,
    float* __restrict__ y)
{
  const int nt = blockIdx.x, mt = blockIdx.y, e = blockIdx.z;
  const int tid = threadIdx.x, lane = tid & 63, wid = tid >> 6;
  const int wr = wid >> 1, wc = wid & 1;
  const int l15 = lane & 15, l4 = lane >> 4;

  __shared__ __align__(16) ushort Al[BM * BK];
  __shared__ __align__(16) ushort Bl[BN * BK];
  __shared__ int tokc[BM];
  __shared__ float scc[BM];

  if (tid < BM) {
    int tk = tok_slot[e * CAP + mt * BM + tid];
    tokc[tid] = tk;
    scc[tid] = (tk >= 0) ? scores[tk] : 0.f;
  }

  const int n0 = nt * BN;
  const int rlane = lane >> 2, oct = lane & 3;
  const size_t hrow0 = (size_t)(e * CAP + mt * BM);

  const ushort* srcA[2]; const ushort* srcB[2];
  int ldsoff[2];
#pragma unroll
  for (int c = 0; c < 2; ++c) {
    int chunk = wid * 2 + c;
    int row = chunk * 16 + rlane;
    srcA[c] = h + (hrow0 + row) * DF + oct * 8;
    srcB[c] = wdt + ((size_t)e * DH + n0 + row) * DF + oct * 8;
    ldsoff[c] = chunk * 512;
  }

  f32x4 acc[4][4];
#pragma unroll
  for (int i = 0; i < 4; ++i)
#pragma unroll
    for (int j = 0; j < 4; ++j) acc[i][j] = (f32x4){0.f, 0.f, 0.f, 0.f};

  for (int kk = 0; kk < DF; kk += BK) {
    __syncthreads();
#pragma unroll
    for (int c = 0; c < 2; ++c) {
      gload16(srcA[c] + kk, &Al[ldsoff[c]]);
      gload16(srcB[c] + kk, &Bl[ldsoff[c]]);
    }
    __syncthreads();
    bf16x8 af[4];
#pragma unroll
    for (int i = 0; i < 4; ++i)
      af[i] = *(const bf16x8*)&Al[(wr * 64 + i * 16 + l15) * BK + l4 * 8];
#pragma unroll
    for (int j = 0; j < 4; ++j) {
      bf16x8 bf = *(const bf16x8*)&Bl[(wc * 64 + j * 16 + l15) * BK + l4 * 8];
#pragma unroll
      for (int i = 0; i < 4; ++i)
        acc[i][j] = __builtin_amdgcn_mfma_f32_16x16x32_bf16(af[i], bf, acc[i][j], 0, 0, 0);
    }
  }
  int tkr[4][4]; float sr[4][4];
#pragma unroll
  for (int i = 0; i < 4; ++i)
#pragma unroll
    for (int r = 0; r < 4; ++r) {
      int rl = wr * 64 + i * 16 + l4 * 4 + r;
      tkr[i][r] = tokc[rl];
      sr[i][r]  = scc[rl];
    }
#pragma unroll
  for (int j = 0; j < 4; ++j) {
    int col = n0 + wc * 64 + j * 16 + l15;
#pragma unroll
    for (int i = 0; i < 4; ++i)
#pragma unroll
      for (int r = 0; r < 4; ++r)
        if (tkr[i][r] >= 0)
          y[(size_t)tkr[i][r] * DH + col] = acc[i][j][r] * sr[i][r];
  }
}

// ================= v1 fallback kernels (proven, used if ws too small) =================
__global__ __launch_bounds__(256, 2) void gemm_gateup(
    const float* __restrict__ x, const float* __restrict__ wg,
    const float* __restrict__ wu, const int* __restrict__ tok_slot,
    ushort* __restrict__ h)
{
  const int nt = blockIdx.x, mt = blockIdx.y, e = blockIdx.z;
  const int tid = threadIdx.x;
  const int lane = tid & 63, wid = tid >> 6;
  const int wr = wid >> 1, wc = wid & 1;
  const int l15 = lane & 15, l4 = lane >> 4;

  __shared__ __align__(16) ushort Al[BM * LDS_STR];
  __shared__ __align__(16) ushort Bg2[BN * LDS_STR];
  __shared__ __align__(16) ushort Bu2[BN * LDS_STR];
  __shared__ int tokc[BM];

  if (tid < BM) tokc[tid] = tok_slot[e * CAP + mt * BM + tid];

  f32x4 accG[4][4], accU[4][4];
#pragma unroll
  for (int i = 0; i < 4; ++i)
#pragma unroll
    for (int j = 0; j < 4; ++j) {
      accG[i][j] = (f32x4){0.f, 0.f, 0.f, 0.f};
      accU[i][j] = (f32x4){0.f, 0.f, 0.f, 0.f};
    }
  const int n0 = nt * BN;
  const int bn = tid & 127, bkh = tid >> 7;
  const int nglob = n0 + bn;
  const bool nv = (nglob < DF);
  const float* wgb = wg + (size_t)e * DH * DF + nglob;
  const float* wub = wu + (size_t)e * DH * DF + nglob;

  for (int kk = 0; kk < DH; kk += BK) {
    __syncthreads();
#pragma unroll
    for (int i = 0; i < 2; ++i) {
      int u = tid + 256 * i;
      int row = u >> 2, oct = u & 3;
      int tk = tokc[row];
      float4 v0 = {0.f,0.f,0.f,0.f}, v1 = {0.f,0.f,0.f,0.f};
      if (tk >= 0) {
        const float* p = x + (size_t)tk * DH + kk + oct * 8;
        v0 = *(const float4*)p; v1 = *(const float4*)(p + 4);
      }
      uint4 pk = { pk2(v0.x, v0.y), pk2(v0.z, v0.w), pk2(v1.x, v1.y), pk2(v1.z, v1.w) };
      *(uint4*)&Al[row * LDS_STR + oct * 8] = pk;
    }
#pragma unroll
    for (int o2 = 0; o2 < 2; ++o2) {
      int klo = kk + bkh * 16 + o2 * 8;
      const float* pg = wgb + (size_t)klo * DF;
      const float* pu = wub + (size_t)klo * DF;
      float g[8], uu[8];
#pragma unroll
      for (int j = 0; j < 8; ++j) {
        g[j]  = nv ? pg[(size_t)j * DF] : 0.f;
        uu[j] = nv ? pu[(size_t)j * DF] : 0.f;
      }
      uint4 pkg = { pk2(g[0],g[1]),  pk2(g[2],g[3]),  pk2(g[4],g[5]),  pk2(g[6],g[7]) };
      uint4 pku = { pk2(uu[0],uu[1]), pk2(uu[2],uu[3]), pk2(uu[4],uu[5]), pk2(uu[6],uu[7]) };
      int oc = bkh * 2 + o2;
      *(uint4*)&Bg2[bn * LDS_STR + oc * 8] = pkg;
      *(uint4*)&Bu2[bn * LDS_STR + oc * 8] = pku;
    }
    __syncthreads();
    bf16x8 af[4];
#pragma unroll
    for (int i = 0; i < 4; ++i)
      af[i] = *(const bf16x8*)&Al[(wr * 64 + i * 16 + l15) * LDS_STR + l4 * 8];
#pragma unroll
    for (int j = 0; j < 4; ++j) {
      bf16x8 bgf = *(const bf16x8*)&Bg2[(wc * 64 + j * 16 + l15) * LDS_STR + l4 * 8];
      bf16x8 buf = *(const bf16x8*)&Bu2[(wc * 64 + j * 16 + l15) * LDS_STR + l4 * 8];
#pragma unroll
      for (int i = 0; i < 4; ++i) {
        accG[i][j] = __builtin_amdgcn_mfma_f32_16x16x32_bf16(af[i], bgf, accG[i][j], 0, 0, 0);
        accU[i][j] = __builtin_amdgcn_mfma_f32_16x16x32_bf16(af[i], buf, accU[i][j], 0, 0, 0);
      }
    }
  }
  const int rowg0 = e * CAP + mt * BM + wr * 64;
#pragma unroll
  for (int j = 0; j < 4; ++j) {
    int col = n0 + wc * 64 + j * 16 + l15;
    if (col < DF) {
#pragma unroll
      for (int i = 0; i < 4; ++i)
#pragma unroll
        for (int r = 0; r < 4; ++r) {
          int row = rowg0 + i * 16 + l4 * 4 + r;
          float gv = accG[i][j][r];
          float uv = accU[i][j][r];
          h[(size_t)row * DF + col] = bf16bits(gv / (1.f + __expf(-gv)) * uv);
        }
    }
  }
}

__global__ __launch_bounds__(256, 2) void gemm_down(
    const ushort* __restrict__ h, const float* __restrict__ wd,
    const int* __restrict__ tok_slot, const float* __restrict__ scores,
    float* __restrict__ y)
{
  const int nt = blockIdx.x, mt = blockIdx.y, e = blockIdx.z;
  const int tid = threadIdx.x;
  const int lane = tid & 63, wid = tid >> 6;
  const int wr = wid >> 1, wc = wid & 1;
  const int l15 = lane & 15, l4 = lane >> 4;

  __shared__ __align__(16) ushort Al[BM * LDS_STR];
  __shared__ __align__(16) ushort Bl2[BN * LDS_STR];
  __shared__ int tokc[BM];
  __shared__ float scc[BM];

  if (tid < BM) {
    int tk = tok_slot[e * CAP + mt * BM + tid];
    tokc[tid] = tk;
    scc[tid] = (tk >= 0) ? scores[tk] : 0.f;
  }
  f32x4 acc[4][4];
#pragma unroll
  for (int i = 0; i < 4; ++i)
#pragma unroll
    for (int j = 0; j < 4; ++j) acc[i][j] = (f32x4){0.f, 0.f, 0.f, 0.f};

  const int n0 = nt * BN;
  const int bn = tid & 127, bkh = tid >> 7;
  const float* wdb = wd + (size_t)e * DF * DH + n0 + bn;
  const size_t hrow0 = (size_t)(e * CAP + mt * BM);

  for (int kk = 0; kk < DF; kk += BK) {
    __syncthreads();
#pragma unroll
    for (int i = 0; i < 2; ++i) {
      int u = tid + 256 * i;
      int row = u >> 2, oct = u & 3;
      uint4 v = *(const uint4*)&h[(hrow0 + row) * DF + kk + oct * 8];
      *(uint4*)&Al[row * LDS_STR + oct * 8] = v;
    }
#pragma unroll
    for (int o2 = 0; o2 < 2; ++o2) {
      int klo = kk + bkh * 16 + o2 * 8;
      const float* p = wdb + (size_t)klo * DH;
      float g[8];
#pragma unroll
      for (int j = 0; j < 8; ++j) g[j] = p[(size_t)j * DH];
      uint4 pkv = { pk2(g[0],g[1]), pk2(g[2],g[3]), pk2(g[4],g[5]), pk2(g[6],g[7]) };
      *(uint4*)&Bl2[bn * LDS_STR + (bkh * 2 + o2) * 8] = pkv;
    }
    __syncthreads();
    bf16x8 af[4];
#pragma unroll
    for (int i = 0; i < 4; ++i)
      af[i] = *(const bf16x8*)&Al[(wr * 64 + i * 16 + l15) * LDS_STR + l4 * 8];
#pragma unroll
    for (int j = 0; j < 4; ++j) {
      bf16x8 bf = *(const bf16x8*)&Bl2[(wc * 64 + j * 16 + l15) * LDS_STR + l4 * 8];
#pragma unroll
      for (int i = 0; i < 4; ++i)
        acc[i][j] = __builtin_amdgcn_mfma_f32_16x16x32_bf16(af[i], bf, acc[i][j], 0, 0, 0);
    }
  }
  int tkr[4][4]; float sr[4][4];
#pragma unroll
  for (int i = 0; i < 4; ++i)
#pragma unroll
    for (int r = 0; r < 4; ++r) {
      int rl = wr * 64 + i * 16 + l4 * 4 + r;
      tkr[i][r] = tokc[rl];
      sr[i][r]  = scc[rl];
    }
#pragma unroll
  for (int j = 0; j < 4; ++j) {
    int col = n0 + wc * 64 + j * 16 + l15;
#pragma unroll
    for (int i = 0; i < 4; ++i)
#pragma unroll
      for (int r = 0; r < 4; ++r)
        if (tkr[i][r] >= 0)
          y[(size_t)tkr[i][r] * DH + col] = acc[i][j][r] * sr[i][r];
  }
}

extern "C" void kernel_launch(void* const* d_in, const int* in_sizes, int n_in,
                              void* d_out, int out_size, void* d_ws, size_t ws_size,
                              hipStream_t stream) {
  const float* x   = (const float*)d_in[0];
  const int*   idx = (const int*)d_in[1];
  const float* sc  = (const float*)d_in[2];
  const float* wg  = (const float*)d_in[3];
  const float* wu  = (const float*)d_in[4];
  const float* wd  = (const float*)d_in[5];
  float* y = (float*)d_out;

  // ws layout
  const size_t OFF_H   = 65536;                                  // tok_slot in [0,64K)
  const size_t SZ_H    = (size_t)NE * CAP * DF * 2;              // 28,180,480
  const size_t OFF_XB  = OFF_H + SZ_H;                           // 28,246,016
  const size_t SZ_XB   = (size_t)NTOK * DH * 2;                  // 33,554,432
  const size_t OFF_WGT = OFF_XB + SZ_XB;
  const size_t SZ_W    = (size_t)NE * DH * DF * 2;               // 45,088,768
  const size_t OFF_WUT = OFF_WGT + SZ_W;
  const size_t OFF_WDT = OFF_WUT + SZ_W;
  const size_t NEED    = OFF_WDT + SZ_W;                         // ~188 MB

  int* tok_slot = (int*)d_ws;
  ushort* h = (ushort*)((char*)d_ws + OFF_H);

  hipMemsetAsync(d_out, 0, (size_t)out_size * sizeof(float), stream);
  hipLaunchKernelGGL(routing_kernel, dim3(1), dim3(256), 0, stream, idx, tok_slot);

  if (ws_size >= NEED) {
    ushort* xb  = (ushort*)((char*)d_ws + OFF_XB);
    ushort* wgt = (ushort*)((char*)d_ws + OFF_WGT);
    ushort* wut = (ushort*)((char*)d_ws + OFF_WUT);
    ushort* wdt = (ushort*)((char*)d_ws + OFF_WDT);

    hipLaunchKernelGGL(convert_x, dim3(NTOK * DH / 2048), dim3(256), 0, stream, x, xb);
    hipLaunchKernelGGL(transpose_cvt, dim3((DF + 63) / 64, DH / 64, NE), dim3(256), 0, stream,
                       wg, wgt, DH, DF);
    hipLaunchKernelGGL(transpose_cvt, dim3((DF + 63) / 64, DH / 64, NE), dim3(256), 0, stream,
                       wu, wut, DH, DF);
    hipLaunchKernelGGL(transpose_cvt, dim3(DH / 64, (DF + 63) / 64, NE), dim3(256), 0, stream,
                       wd, wdt, DF, DH);

    hipLaunchKernelGGL(gemm_gateup2, dim3((DF + BN - 1) / BN, CAP / BM, NE), dim3(256), 0, stream,
                       xb, wgt, wut, tok_slot, h);
    hipLaunchKernelGGL(gemm_down2, dim3(DH / BN, CAP / BM, NE), dim3(256), 0, stream,
                       h, wdt, tok_slot, sc, y);
  } else {
    hipLaunchKernelGGL(gemm_gateup, dim3((DF + BN - 1) / BN, CAP / BM, NE), dim3(256), 0, stream,
                       x, wg, wu, tok_slot, h);
    hipLaunchKernelGGL(gemm_down, dim3(DH / BN, CAP / BM, NE), dim3(256), 0, stream,
                       h, wd, tok_slot, sc, y);
  }
}

// Round 4
// 333.905 us; speedup vs baseline: 5.4935x; 1.2325x over previous
//
#include <hip/hip_runtime.h>
#include <hip/hip_bf16.h>
#include <cstdint>
#include <cstddef>

#define NTOK 8192
#define DH   2048
#define DF   1376
#define DFP  1408      // h row stride (K-padded for down-GEMM BK=64)
#define NE   8
#define CAP  1280

typedef __bf16 bf16x8 __attribute__((ext_vector_type(8)));
typedef float  f32x4  __attribute__((ext_vector_type(4)));

#define BARRIER() asm volatile("s_barrier" ::: "memory")
#define WAITV0()  asm volatile("s_waitcnt vmcnt(0)" ::: "memory")
#define WAITV4()  asm volatile("s_waitcnt vmcnt(4)" ::: "memory")
#define WAITV6()  asm volatile("s_waitcnt vmcnt(6)" ::: "memory")
#define SETPRIO(n) __builtin_amdgcn_s_setprio(n)

__device__ __forceinline__ uint32_t pk2(float a, float b) {
  float2 f; f.x = a; f.y = b;
  union { __hip_bfloat162 h; uint32_t u; } cv;
  cv.h = __float22bfloat162_rn(f);
  return cv.u;
}
__device__ __forceinline__ ushort bf16bits(float a) {
  return (ushort)(pk2(a, 0.f) & 0xFFFFu);
}
// async global->LDS, 16B/lane; lds ptr wave-uniform, HW adds lane*16
__device__ __forceinline__ void gload16(const ushort* g, ushort* l) {
  __builtin_amdgcn_global_load_lds(
      (const __attribute__((address_space(1))) uint32_t*)(const void*)g,
      (__attribute__((address_space(3))) uint32_t*)(void*)l,
      16, 0, 0);
}

// ---------------- routing ----------------
__global__ void routing_kernel(const int* __restrict__ idx, int* __restrict__ tok_slot,
                               int* __restrict__ tok_keep) {
  __shared__ int cnt[256][NE];
  const int t = threadIdx.x;
  for (int s = t; s < NE * CAP; s += 256) tok_slot[s] = -1;
  unsigned long long cA = 0ull, cB = 0ull;
  const int per = NTOK / 256, base = t * per;
  for (int i = 0; i < per; ++i) {
    int e = idx[base + i];
    unsigned long long inc = 1ull << ((e & 3) * 16);
    if (e < 4) cA += inc; else cB += inc;
  }
#pragma unroll
  for (int e = 0; e < 4; ++e) cnt[t][e]     = (int)((cA >> (e * 16)) & 0xFFFF);
#pragma unroll
  for (int e = 0; e < 4; ++e) cnt[t][4 + e] = (int)((cB >> (e * 16)) & 0xFFFF);
  __syncthreads();
  if (t < NE) {
    int run = 0;
    for (int i = 0; i < 256; ++i) { int c = cnt[i][t]; cnt[i][t] = run; run += c; }
  }
  __syncthreads();
  cA = 0ull; cB = 0ull;
#pragma unroll
  for (int e = 0; e < 4; ++e) cA |= (unsigned long long)(cnt[t][e] & 0xFFFF) << (e * 16);
#pragma unroll
  for (int e = 0; e < 4; ++e) cB |= (unsigned long long)(cnt[t][4 + e] & 0xFFFF) << (e * 16);
  for (int i = 0; i < per; ++i) {
    int token = base + i;
    int e = idx[token];
    int sh = (e & 3) * 16;
    int r = (int)(((e < 4 ? cA : cB) >> sh) & 0xFFFF);
    unsigned long long inc = 1ull << sh;
    if (e < 4) cA += inc; else cB += inc;
    bool keep = (r < CAP);
    tok_keep[token] = keep ? 1 : 0;
    if (keep) tok_slot[e * CAP + r] = token;
  }
}

// ---------------- y rows for dropped tokens -> 0 ----------------
__global__ void zero_dropped(const int* __restrict__ keep, float* __restrict__ y) {
  if (keep[blockIdx.x]) return;
  float4 z = {0.f, 0.f, 0.f, 0.f};
  float* p = y + (size_t)blockIdx.x * DH + threadIdx.x * 8;
  *(float4*)p = z;
  *(float4*)(p + 4) = z;
}

// ---------------- x f32 -> bf16 ----------------
__global__ void convert_x(const float* __restrict__ x, ushort* __restrict__ xb) {
  int i = (blockIdx.x * 256 + threadIdx.x) * 8;
  float4 a = *(const float4*)(x + i);
  float4 b = *(const float4*)(x + i + 4);
  uint4 p = { pk2(a.x, a.y), pk2(a.z, a.w), pk2(b.x, b.y), pk2(b.z, b.w) };
  *(uint4*)(xb + i) = p;
}

// ---------------- w [E][K][N] f32 -> [E][N][K] bf16 ----------------
__global__ __launch_bounds__(256) void transpose_cvt(
    const float* __restrict__ in, ushort* __restrict__ out, int K, int N) {
  __shared__ ushort T[64][72];
  const int tid = threadIdx.x;
  const int n0 = blockIdx.x * 64, k0 = blockIdx.y * 64;
  const size_t eoff_in  = (size_t)blockIdx.z * K * N;
  const size_t eoff_out = (size_t)blockIdx.z * N * K;
  const int kr = tid >> 4;
  const int nc = (tid & 15) * 4;
#pragma unroll
  for (int it = 0; it < 4; ++it) {
    int k = k0 + kr + it * 16;
    int n = n0 + nc;
    float4 v = {0.f, 0.f, 0.f, 0.f};
    if (k < K && n + 4 <= N) v = *(const float4*)(in + eoff_in + (size_t)k * N + n);
    T[nc + 0][kr + it * 16] = bf16bits(v.x);
    T[nc + 1][kr + it * 16] = bf16bits(v.y);
    T[nc + 2][kr + it * 16] = bf16bits(v.z);
    T[nc + 3][kr + it * 16] = bf16bits(v.w);
  }
  __syncthreads();
  const int nr = tid >> 2;
  const int kc = tid & 3;
#pragma unroll
  for (int it = 0; it < 2; ++it) {
    int kloc = kc * 16 + it * 8;
    int n = n0 + nr, k = k0 + kloc;
    if (n < N && k + 8 <= K)
      *(uint4*)(out + eoff_out + (size_t)n * K + k) = *(const uint4*)&T[nr][kloc];
  }
}

// ---------------- zero h pad cols [DF, DFP) ----------------
__global__ void pad_h(ushort* __restrict__ h) {
  int idx = blockIdx.x * 512 + threadIdx.x;   // 40960 total
  int row = idx >> 2, q = idx & 3;
  uint4 z = {0u, 0u, 0u, 0u};
  *(uint4*)(h + (size_t)row * DFP + DF + q * 8) = z;
}

// ======================================================================
// GEMM1 (tile 256Mx128N, BK=64, 8 waves 4Mx2N): h = silu(Xe*Wg).*(Xe*Wu)
// LDS (static 128KB): A[2][32KB]@0, Bg[2][16KB]@64K, Bu[2][16KB]@96K
// Swizzle: byte ^= ((row&7)<<4), applied to write SOURCE (pre-swizzled
// global addr) and to read offsets. k1 offsets: XOR after +64 (no carry).
// Phases per K-tile t (buf p=t&1):
//  ph1: rd a0,bg0 | stage Bu(t+1)->p^1    | G-MFMA k0
//  ph2: rd a1,bg1 |                       | G-MFMA k1
//  ph3: rd bu0    | stage A0,Bg(t+2)->p   | U-MFMA k0
//  ph4: rd bu1    | stage A1(t+2)->p      | U-MFMA k1, vmcnt(6)
// ======================================================================
__global__ __launch_bounds__(512, 1) void gemm_gateup3(
    const ushort* __restrict__ xb, const ushort* __restrict__ wgt,
    const ushort* __restrict__ wut, const int* __restrict__ tok_slot,
    ushort* __restrict__ h)
{
  __shared__ __align__(16) char smbuf[131072];
  char* sm = smbuf;
  const int tid = threadIdx.x, lane = tid & 63, wid = tid >> 6;
  const int wr = wid >> 1, wc = wid & 1;
  const int l15 = lane & 15, l4 = lane >> 4;

  // XCD swizzle: 440 blocks = 8 XCDs x 55 (one expert: 5 mt x 11 nt)
  int wgid = (blockIdx.x & 7) * 55 + (blockIdx.x >> 3);
  const int e = wgid / 55;
  const int rem = wgid - e * 55;
  const int mt = rem / 11, nt = rem - (rem / 11) * 11;
  const int n0 = nt * 128;

  // staging sources (pre-swizzled, loop-invariant)
  const ushort* srcA[2][2]; const ushort* srcBg[2]; const ushort* srcBu[2];
#pragma unroll
  for (int u = 0; u < 2; ++u)
#pragma unroll
    for (int jj = 0; jj < 2; ++jj) {
      int o = u * 16384 + (jj * 8 + wid) * 1024 + lane * 16;
      int os = o ^ (((o >> 7) & 7) << 4);
      int row = os >> 7, kb = os & 127;
      int tk = tok_slot[e * CAP + mt * 256 + row];
      if (tk < 0) tk = 0;                      // finite garbage; discarded later
      srcA[u][jj] = xb + (size_t)tk * DH + (kb >> 1);
    }
#pragma unroll
  for (int jj = 0; jj < 2; ++jj) {
    int o = (jj * 8 + wid) * 1024 + lane * 16;
    int os = o ^ (((o >> 7) & 7) << 4);
    int row = os >> 7, kb = os & 127;
    int n = n0 + row; if (n > DF - 1) n = DF - 1;
    srcBg[jj] = wgt + ((size_t)e * DF + n) * DH + (kb >> 1);
    srcBu[jj] = wut + ((size_t)e * DF + n) * DH + (kb >> 1);
  }
  // fragment read offsets, k0 and k1 separately swizzled (XOR AFTER +64)
  int aoff0[4], aoff1[4], boff0[4], boff1[4];
#pragma unroll
  for (int i = 0; i < 4; ++i) {
    int row = wr * 64 + i * 16 + l15;
    int r4 = (row & 7) << 4;
    aoff0[i] = row * 128 + ((l4 * 16) ^ r4);
    aoff1[i] = row * 128 + ((l4 * 16 + 64) ^ r4);
  }
#pragma unroll
  for (int j = 0; j < 4; ++j) {
    int row = wc * 64 + j * 16 + l15;
    int r4 = (row & 7) << 4;
    boff0[j] = row * 128 + ((l4 * 16) ^ r4);
    boff1[j] = row * 128 + ((l4 * 16 + 64) ^ r4);
  }
  const int dst0 = wid * 1024, dst1 = (8 + wid) * 1024;

  f32x4 accG[4][4], accU[4][4];
#pragma unroll
  for (int i = 0; i < 4; ++i)
#pragma unroll
    for (int j = 0; j < 4; ++j) {
      accG[i][j] = (f32x4){0.f, 0.f, 0.f, 0.f};
      accU[i][j] = (f32x4){0.f, 0.f, 0.f, 0.f};
    }

  const int NT = DH / 64;  // 32
  // prologue: tile0 full -> buf0 (8 loads); tile1 A,Bg -> buf1 (6 loads)
  gload16(srcA[0][0], (ushort*)(sm + dst0));
  gload16(srcA[0][1], (ushort*)(sm + dst1));
  gload16(srcA[1][0], (ushort*)(sm + 16384 + dst0));
  gload16(srcA[1][1], (ushort*)(sm + 16384 + dst1));
  gload16(srcBg[0],   (ushort*)(sm + 65536 + dst0));
  gload16(srcBg[1],   (ushort*)(sm + 65536 + dst1));
  gload16(srcBu[0],   (ushort*)(sm + 98304 + dst0));
  gload16(srcBu[1],   (ushort*)(sm + 98304 + dst1));
  gload16(srcA[0][0] + 64, (ushort*)(sm + 32768 + dst0));
  gload16(srcA[0][1] + 64, (ushort*)(sm + 32768 + dst1));
  gload16(srcA[1][0] + 64, (ushort*)(sm + 32768 + 16384 + dst0));
  gload16(srcA[1][1] + 64, (ushort*)(sm + 32768 + 16384 + dst1));
  gload16(srcBg[0] + 64,   (ushort*)(sm + 65536 + 16384 + dst0));
  gload16(srcBg[1] + 64,   (ushort*)(sm + 65536 + 16384 + dst1));
  WAITV6();
  BARRIER();

  bf16x8 a0[4], a1[4], bg[4], bu[4];
  for (int t = 0; t < NT; ++t) {
    const int p = t & 1;
    char* Ab  = sm + p * 32768;
    char* Bgb = sm + 65536 + p * 16384;
    char* Bub = sm + 98304 + p * 16384;
    char* Bun = sm + 98304 + (p ^ 1) * 16384;
    // ---- ph1
#pragma unroll
    for (int i = 0; i < 4; ++i) a0[i] = *(const bf16x8*)(Ab + aoff0[i]);
#pragma unroll
    for (int j = 0; j < 4; ++j) bg[j] = *(const bf16x8*)(Bgb + boff0[j]);
    if (t + 1 < NT) {
      int kk = (t + 1) * 64;
      gload16(srcBu[0] + kk, (ushort*)(Bun + dst0));
      gload16(srcBu[1] + kk, (ushort*)(Bun + dst1));
    }
    BARRIER();
    SETPRIO(1);
#pragma unroll
    for (int j = 0; j < 4; ++j)
#pragma unroll
      for (int i = 0; i < 4; ++i)
        accG[i][j] = __builtin_amdgcn_mfma_f32_16x16x32_bf16(a0[i], bg[j], accG[i][j], 0, 0, 0);
    SETPRIO(0);
    BARRIER();
    // ---- ph2
#pragma unroll
    for (int i = 0; i < 4; ++i) a1[i] = *(const bf16x8*)(Ab + aoff1[i]);
#pragma unroll
    for (int j = 0; j < 4; ++j) bg[j] = *(const bf16x8*)(Bgb + boff1[j]);
    BARRIER();
    SETPRIO(1);
#pragma unroll
    for (int j = 0; j < 4; ++j)
#pragma unroll
      for (int i = 0; i < 4; ++i)
        accG[i][j] = __builtin_amdgcn_mfma_f32_16x16x32_bf16(a1[i], bg[j], accG[i][j], 0, 0, 0);
    SETPRIO(0);
    BARRIER();
    // ---- ph3
#pragma unroll
    for (int j = 0; j < 4; ++j) bu[j] = *(const bf16x8*)(Bub + boff0[j]);
    if (t + 2 < NT) {
      int kk = (t + 2) * 64;
      gload16(srcA[0][0] + kk, (ushort*)(Ab + dst0));
      gload16(srcA[0][1] + kk, (ushort*)(Ab + dst1));
      gload16(srcBg[0] + kk,   (ushort*)(Bgb + dst0));
      gload16(srcBg[1] + kk,   (ushort*)(Bgb + dst1));
    }
    BARRIER();
    SETPRIO(1);
#pragma unroll
    for (int j = 0; j < 4; ++j)
#pragma unroll
      for (int i = 0; i < 4; ++i)
        accU[i][j] = __builtin_amdgcn_mfma_f32_16x16x32_bf16(a0[i], bu[j], accU[i][j], 0, 0, 0);
    SETPRIO(0);
    BARRIER();
    // ---- ph4
#pragma unroll
    for (int j = 0; j < 4; ++j) bu[j] = *(const bf16x8*)(Bub + boff1[j]);
    if (t + 2 < NT) {
      int kk = (t + 2) * 64;
      gload16(srcA[1][0] + kk, (ushort*)(Ab + 16384 + dst0));
      gload16(srcA[1][1] + kk, (ushort*)(Ab + 16384 + dst1));
    }
    BARRIER();
    SETPRIO(1);
#pragma unroll
    for (int j = 0; j < 4; ++j)
#pragma unroll
      for (int i = 0; i < 4; ++i)
        accU[i][j] = __builtin_amdgcn_mfma_f32_16x16x32_bf16(a1[i], bu[j], accU[i][j], 0, 0, 0);
    SETPRIO(0);
    if (t >= NT - 2) { WAITV0(); } else { WAITV6(); }
    BARRIER();
  }
  // epilogue: SwiGLU -> h (stride DFP)
  const size_t rowbase = (size_t)(e * CAP + mt * 256 + wr * 64);
#pragma unroll
  for (int j = 0; j < 4; ++j) {
    int col = n0 + wc * 64 + j * 16 + l15;
    if (col < DF) {
#pragma unroll
      for (int i = 0; i < 4; ++i)
#pragma unroll
        for (int r = 0; r < 4; ++r) {
          size_t row = rowbase + i * 16 + l4 * 4 + r;
          float gv = accG[i][j][r], uv = accU[i][j][r];
          h[row * DFP + col] = bf16bits(gv / (1.f + __expf(-gv)) * uv);
        }
    }
  }
}

// ======================================================================
// GEMM2 (tile 256Mx128N, BK=64, 8 waves 4Mx2N): y[token] = (H*Wd)*score
// LDS (static 98KB): A[2][32KB]@0, B[2][16KB]@64K, tokc@96K, scc@97K
// Phases per K-tile t (buf p):
//  ph1: rd a0,b0[01] | stage B(t+1)->p^1   | MFMA k0 j01
//  ph2: rd b0[23]    |                     | MFMA k0 j23
//  ph3: rd a1,b1[01] |                     | MFMA k1 j01
//  ph4: rd b1[23]    | stage A0,A1(t+2)->p | MFMA k1 j23, vmcnt(4)
// ======================================================================
__global__ __launch_bounds__(512, 1) void gemm_down3(
    const ushort* __restrict__ h, const ushort* __restrict__ wdt,
    const int* __restrict__ tok_slot, const float* __restrict__ scores,
    float* __restrict__ y)
{
  __shared__ __align__(16) char smbuf[100352];
  char* sm = smbuf;
  int* tokc = (int*)(sm + 98304);
  float* scc = (float*)(sm + 99328);
  const int tid = threadIdx.x, lane = tid & 63, wid = tid >> 6;
  const int wr = wid >> 1, wc = wid & 1;
  const int l15 = lane & 15, l4 = lane >> 4;

  // XCD swizzle: 640 blocks = 8 XCDs x 80 (one expert: 5 mt x 16 nt)
  int wgid = (blockIdx.x & 7) * 80 + (blockIdx.x >> 3);
  const int e = wgid / 80;
  const int rem = wgid - e * 80;
  const int mt = rem / 16, nt = rem & 15;
  const int n0 = nt * 128;

  if (tid < 256) {
    int tk = tok_slot[e * CAP + mt * 256 + tid];
    tokc[tid] = tk;
    scc[tid] = (tk >= 0) ? scores[tk] : 0.f;
  }
  __syncthreads();

  const size_t hrow0 = (size_t)(e * CAP + mt * 256);
  const ushort* srcA[2][2]; const ushort* srcB[2];
#pragma unroll
  for (int u = 0; u < 2; ++u)
#pragma unroll
    for (int jj = 0; jj < 2; ++jj) {
      int o = u * 16384 + (jj * 8 + wid) * 1024 + lane * 16;
      int os = o ^ (((o >> 7) & 7) << 4);
      int row = os >> 7, kb = os & 127;
      srcA[u][jj] = h + (hrow0 + row) * DFP + (kb >> 1);
    }
#pragma unroll
  for (int jj = 0; jj < 2; ++jj) {
    int o = (jj * 8 + wid) * 1024 + lane * 16;
    int os = o ^ (((o >> 7) & 7) << 4);
    int row = os >> 7, kb = os & 127;
    srcB[jj] = wdt + ((size_t)e * DH + n0 + row) * DF + (kb >> 1);  // stride DF
  }
  int aoff0[4], aoff1[4], boff0[4], boff1[4];
#pragma unroll
  for (int i = 0; i < 4; ++i) {
    int row = wr * 64 + i * 16 + l15;
    int r4 = (row & 7) << 4;
    aoff0[i] = row * 128 + ((l4 * 16) ^ r4);
    aoff1[i] = row * 128 + ((l4 * 16 + 64) ^ r4);
  }
#pragma unroll
  for (int j = 0; j < 4; ++j) {
    int row = wc * 64 + j * 16 + l15;
    int r4 = (row & 7) << 4;
    boff0[j] = row * 128 + ((l4 * 16) ^ r4);
    boff1[j] = row * 128 + ((l4 * 16 + 64) ^ r4);
  }
  const int dst0 = wid * 1024, dst1 = (8 + wid) * 1024;

  f32x4 acc[4][4];
#pragma unroll
  for (int i = 0; i < 4; ++i)
#pragma unroll
    for (int j = 0; j < 4; ++j) acc[i][j] = (f32x4){0.f, 0.f, 0.f, 0.f};

  const int NT = DFP / 64;  // 22 (A pad cols zero; B tail killed by A zeros)
  // prologue: tile0 (A+B) -> buf0 (6); tile1 A -> buf1 (4)
  gload16(srcA[0][0], (ushort*)(sm + dst0));
  gload16(srcA[0][1], (ushort*)(sm + dst1));
  gload16(srcA[1][0], (ushort*)(sm + 16384 + dst0));
  gload16(srcA[1][1], (ushort*)(sm + 16384 + dst1));
  gload16(srcB[0],    (ushort*)(sm + 65536 + dst0));
  gload16(srcB[1],    (ushort*)(sm + 65536 + dst1));
  gload16(srcA[0][0] + 64, (ushort*)(sm + 32768 + dst0));
  gload16(srcA[0][1] + 64, (ushort*)(sm + 32768 + dst1));
  gload16(srcA[1][0] + 64, (ushort*)(sm + 32768 + 16384 + dst0));
  gload16(srcA[1][1] + 64, (ushort*)(sm + 32768 + 16384 + dst1));
  WAITV4();
  BARRIER();

  bf16x8 a0[4], a1[4], b0, b1;
  for (int t = 0; t < NT; ++t) {
    const int p = t & 1;
    char* Ab = sm + p * 32768;
    char* Bb = sm + 65536 + p * 16384;
    char* Bn = sm + 65536 + (p ^ 1) * 16384;
    // ---- ph1
#pragma unroll
    for (int i = 0; i < 4; ++i) a0[i] = *(const bf16x8*)(Ab + aoff0[i]);
    b0 = *(const bf16x8*)(Bb + boff0[0]);
    b1 = *(const bf16x8*)(Bb + boff0[1]);
    if (t + 1 < NT) {
      int kk = (t + 1) * 64;
      gload16(srcB[0] + kk, (ushort*)(Bn + dst0));
      gload16(srcB[1] + kk, (ushort*)(Bn + dst1));
    }
    BARRIER();
    SETPRIO(1);
#pragma unroll
    for (int i = 0; i < 4; ++i) {
      acc[i][0] = __builtin_amdgcn_mfma_f32_16x16x32_bf16(a0[i], b0, acc[i][0], 0, 0, 0);
      acc[i][1] = __builtin_amdgcn_mfma_f32_16x16x32_bf16(a0[i], b1, acc[i][1], 0, 0, 0);
    }
    SETPRIO(0);
    BARRIER();
    // ---- ph2
    b0 = *(const bf16x8*)(Bb + boff0[2]);
    b1 = *(const bf16x8*)(Bb + boff0[3]);
    BARRIER();
    SETPRIO(1);
#pragma unroll
    for (int i = 0; i < 4; ++i) {
      acc[i][2] = __builtin_amdgcn_mfma_f32_16x16x32_bf16(a0[i], b0, acc[i][2], 0, 0, 0);
      acc[i][3] = __builtin_amdgcn_mfma_f32_16x16x32_bf16(a0[i], b1, acc[i][3], 0, 0, 0);
    }
    SETPRIO(0);
    BARRIER();
    // ---- ph3
#pragma unroll
    for (int i = 0; i < 4; ++i) a1[i] = *(const bf16x8*)(Ab + aoff1[i]);
    b0 = *(const bf16x8*)(Bb + boff1[0]);
    b1 = *(const bf16x8*)(Bb + boff1[1]);
    BARRIER();
    SETPRIO(1);
#pragma unroll
    for (int i = 0; i < 4; ++i) {
      acc[i][0] = __builtin_amdgcn_mfma_f32_16x16x32_bf16(a1[i], b0, acc[i][0], 0, 0, 0);
      acc[i][1] = __builtin_amdgcn_mfma_f32_16x16x32_bf16(a1[i], b1, acc[i][1], 0, 0, 0);
    }
    SETPRIO(0);
    BARRIER();
    // ---- ph4
    b0 = *(const bf16x8*)(Bb + boff1[2]);
    b1 = *(const bf16x8*)(Bb + boff1[3]);
    if (t + 2 < NT) {
      int kk = (t + 2) * 64;
      gload16(srcA[0][0] + kk, (ushort*)(Ab + dst0));
      gload16(srcA[0][1] + kk, (ushort*)(Ab + dst1));
      gload16(srcA[1][0] + kk, (ushort*)(Ab + 16384 + dst0));
      gload16(srcA[1][1] + kk, (ushort*)(Ab + 16384 + dst1));
    }
    BARRIER();
    SETPRIO(1);
#pragma unroll
    for (int i = 0; i < 4; ++i) {
      acc[i][2] = __builtin_amdgcn_mfma_f32_16x16x32_bf16(a1[i], b0, acc[i][2], 0, 0, 0);
      acc[i][3] = __builtin_amdgcn_mfma_f32_16x16x32_bf16(a1[i], b1, acc[i][3], 0, 0, 0);
    }
    SETPRIO(0);
    if (t >= NT - 2) { WAITV0(); } else { WAITV4(); }
    BARRIER();
  }
  // epilogue: scatter * score
  int tkr[4][4]; float sr[4][4];
#pragma unroll
  for (int i = 0; i < 4; ++i)
#pragma unroll
    for (int r = 0; r < 4; ++r) {
      int rl = wr * 64 + i * 16 + l4 * 4 + r;
      tkr[i][r] = tokc[rl];
      sr[i][r]  = scc[rl];
    }
#pragma unroll
  for (int j = 0; j < 4; ++j) {
    int col = n0 + wc * 64 + j * 16 + l15;
#pragma unroll
    for (int i = 0; i < 4; ++i)
#pragma unroll
      for (int r = 0; r < 4; ++r)
        if (tkr[i][r] >= 0)
          y[(size_t)tkr[i][r] * DH + col] = acc[i][j][r] * sr[i][r];
  }
}

extern "C" void kernel_launch(void* const* d_in, const int* in_sizes, int n_in,
                              void* d_out, int out_size, void* d_ws, size_t ws_size,
                              hipStream_t stream) {
  const float* x   = (const float*)d_in[0];
  const int*   idx = (const int*)d_in[1];
  const float* sc  = (const float*)d_in[2];
  const float* wg  = (const float*)d_in[3];
  const float* wu  = (const float*)d_in[4];
  const float* wd  = (const float*)d_in[5];
  float* y = (float*)d_out;

  // ws layout (~152.6 MB; wdt reuses wgt region after gateup)
  const size_t OFF_KEEP = 40960;                       // tok_slot [0,40960)
  const size_t OFF_H    = 73728;                       // keep [40960,73728)
  const size_t SZ_H     = (size_t)NE * CAP * DFP * 2;  // 28,835,840
  const size_t OFF_XB   = OFF_H + SZ_H;                // 28,909,568
  const size_t SZ_XB    = (size_t)NTOK * DH * 2;       // 33,554,432
  const size_t OFF_WGT  = OFF_XB + SZ_XB;              // 62,464,000
  const size_t SZ_W     = (size_t)NE * DH * DF * 2;    // 45,088,768
  const size_t OFF_WUT  = OFF_WGT + SZ_W;              // 107,552,768

  int* tok_slot = (int*)d_ws;
  int* tok_keep = (int*)((char*)d_ws + OFF_KEEP);
  ushort* hbuf = (ushort*)((char*)d_ws + OFF_H);
  ushort* xb   = (ushort*)((char*)d_ws + OFF_XB);
  ushort* wgt  = (ushort*)((char*)d_ws + OFF_WGT);
  ushort* wut  = (ushort*)((char*)d_ws + OFF_WUT);
  ushort* wdt  = wgt;   // dead after gateup

  hipLaunchKernelGGL(routing_kernel, dim3(1), dim3(256), 0, stream, idx, tok_slot, tok_keep);
  hipLaunchKernelGGL(zero_dropped, dim3(NTOK), dim3(256), 0, stream, tok_keep, y);
  hipLaunchKernelGGL(convert_x, dim3(NTOK * DH / 2048), dim3(256), 0, stream, x, xb);
  hipLaunchKernelGGL(transpose_cvt, dim3((DF + 63) / 64, DH / 64, NE), dim3(256), 0, stream,
                     wg, wgt, DH, DF);
  hipLaunchKernelGGL(transpose_cvt, dim3((DF + 63) / 64, DH / 64, NE), dim3(256), 0, stream,
                     wu, wut, DH, DF);
  hipLaunchKernelGGL(pad_h, dim3(80), dim3(512), 0, stream, hbuf);
  hipLaunchKernelGGL(gemm_gateup3, dim3(440), dim3(512), 0, stream,
                     xb, wgt, wut, tok_slot, hbuf);
  hipLaunchKernelGGL(transpose_cvt, dim3(DH / 64, (DF + 63) / 64, NE), dim3(256), 0, stream,
                     wd, wdt, DF, DH);
  hipLaunchKernelGGL(gemm_down3, dim3(640), dim3(512), 0, stream,
                     hbuf, wdt, tok_slot, sc, y);
}